// Round 10
// baseline (404.576 us; speedup 1.0000x reference)
//
#include <hip/hip_runtime.h>
#include <math.h>

// Problem constants (reference: H=256, N=32, S=256, R=1, CCH=32, L=2048, B=2)
#define LF   1025     // L/2+1

// ---- workspace layout (bytes) ----
#define OFF_ZT   65536
#define OFF_KF   131072
#define OFF_PDF  67371008
#define OFF_DCT  84148224

__device__ __forceinline__ float2 cmulf(float2 a, float2 b){
    return make_float2(a.x*b.x - a.y*b.y, a.x*b.y + a.y*b.x);
}

// e^{-2 pi i r}, 0 <= r < 1 (exact dyadic). v_sin/v_cos take REVOLUTIONS on
// gfx9xx -> no table, no gather, no range reduction needed.
__device__ __forceinline__ float2 twid(float r){
    float s, c;
    asm("v_sin_f32 %0, %1" : "=v"(s) : "v"(r));
    asm("v_cos_f32 %0, %1" : "=v"(c) : "v"(r));
    return make_float2(c, -s);
}
// fast reciprocal (~1 ulp) - tolerance is 7.8e-3, plenty of margin
__device__ __forceinline__ float frcp(float x){
    float y; asm("v_rcp_f32 %0, %1" : "=v"(y) : "v"(x)); return y;
}
// own-wave LDS ordering fence: waits this wave's ds ops; asm volatile+memory
// is also a compiler reorder barrier for the surrounding ds_read/ds_write.
__device__ __forceinline__ void lds_fence(){
    asm volatile("s_waitcnt lgkmcnt(0)" ::: "memory");
}

// FFT buffers: 4 groups x 512, group stride 548 (8-bank offset between groups,
// 1096 words % 32 == 8) + intra-group pad every 16.
#define GS 548
__device__ __forceinline__ int gslot(int g, int s){ return g*GS + s + (s >> 4); }
// post-FFT: bin j lives at gslot(j&3, j>>2)  (X[4s+g] stored at group g, slot s)
__device__ __forceinline__ int binslot(int j){ return gslot(j & 3, j >> 2); }

// ---------------- init: bilinear nodes (fp64 once) ----------------
__global__ void initk(float4* __restrict__ ZT){
    int i = blockIdx.x*256 + threadIdx.x;
    if (i < LF){
        double th = (-2.0*M_PI) * (double)i / 2048.0;
        double cr = cos(th), ci = sin(th);
        double ar = 1.0 + cr, ai = ci;              // 1+w
        double den = ar*ar + ai*ai;
        double nr = 1.0 - cr, ni = -ci;             // 1-w
        double zr = 2.0*(nr*ar + ni*ai)/den;        // z = 2(1-w)/(1+w)
        double zi = 2.0*(ni*ar - nr*ai)/den;
        ZT[i] = make_float4((float)zr, (float)zi, (float)(2.0*ar/den), (float)(-2.0*ai/den));
    }
}

// ---------------- dC (l, h, c) -> DCT (h*32+c, l) ----------------
__global__ void transpose_dC(const float* __restrict__ dC, float* __restrict__ DCT){
    __shared__ float tile[32][33];
    int hc0 = blockIdx.x*32;
    int l0  = blockIdx.y*32;
    int tx = threadIdx.x;
    for (int i = threadIdx.y; i < 32; i += 8)
        tile[i][tx] = dC[(size_t)(l0+i)*8192 + hc0 + tx];
    __syncthreads();
    for (int i = threadIdx.y; i < 32; i += 8)
        DCT[(size_t)(hc0+i)*2048 + l0 + tx] = tile[tx][i];
}

// ---------------- Cauchy + Woodbury -> k_f ----------------
// Round-10: REVERTED to the round-8 form (z=4 blocks of 8 channels + Q-row).
// Round-9's 32-channel merge regressed ~11us: 33-accumulator variant needed
// ~200+ VGPR -> 2 waves/SIMD, and the saved setup redundancy was cheaper than
// the lost latency hiding. frcp kept (verified r8).
__global__ __launch_bounds__(256) void cauchy_k(
                         const float* __restrict__ log_dt, const float* __restrict__ B_ri,
                         const float* __restrict__ P_ri, const float* __restrict__ C_ri,
                         const float* __restrict__ ivw, const float* __restrict__ wimag,
                         const float4* __restrict__ ZT, float2* __restrict__ KF)
{
    const int h  = blockIdx.y;
    const int c0 = blockIdx.z * 8;
    const int l  = blockIdx.x*256 + (int)threadIdx.x;
    __shared__ float wre[32], wim[32], bre[32], bim[32], ppre[32], ppim[32];
    __shared__ float cre[8][32], cim[8][32];
    __shared__ float dt_sh;
    if (threadIdx.x < 32){
        int n = threadIdx.x;
        float dt = expf(log_dt[h]);
        wre[n] = -expf(ivw[h*32+n]) * dt;
        wim[n] = wimag[h*32+n] * dt;
        bre[n] = B_ri[(h*32+n)*2+0];
        bim[n] = B_ri[(h*32+n)*2+1];
        ppre[n] = P_ri[(h*32+n)*2+0];
        ppim[n] = P_ri[(h*32+n)*2+1];
        if (n == 0) dt_sh = dt;
    }
    {
        int i = threadIdx.x;
        int cc = i >> 5, n = i & 31;
        size_t base = (((size_t)(c0+cc)*256 + h)*32 + n)*2;
        cre[cc][n] = C_ri[base+0];
        cim[cc][n] = C_ri[base+1];
    }
    __syncthreads();
    if (l >= LF) return;

    float4 zt = ZT[l];
    const float zx = zt.x, zy = zt.y;
    float r0x[9], r0y[9], r1x[9], r1y[9];
    #pragma unroll
    for (int j=0;j<9;++j){ r0x[j]=0.f; r0y[j]=0.f; r1x[j]=0.f; r1y[j]=0.f; }

    #pragma unroll 1
    for (int n=0; n<32; ++n){
        float wr = wre[n], wi = wim[n];
        float dx = zx - wr;
        float dy = zy - wi;
        float ey = zy + wi;
        float ip = frcp(dx*dx + dy*dy);
        float im = frcp(dx*dx + ey*ey);
        float cpx = dx*ip, cpy = -dy*ip;
        float cmx = dx*im, cmy = -ey*im;
        float br = bre[n], bi = bim[n];
        float t0x = br*cpx - bi*cpy, t0y = br*cpy + bi*cpx;
        float t1x = br*cmx + bi*cmy, t1y = br*cmy - bi*cmx;
        float pr = ppre[n], pi = ppim[n];
        float t2x = pr*cpx - pi*cpy, t2y = pr*cpy + pi*cpx;
        float t3x = pr*cmx + pi*cmy, t3y = pr*cmy - pi*cmx;
        float u0 = t0x+t1x, v0 = t1y-t0y, s0 = t0y+t1y, q0 = t0x-t1x;
        float u1 = t2x+t3x, v1 = t3y-t2y, s1 = t2y+t3y, q1 = t2x-t3x;
        #pragma unroll
        for (int j=0;j<8;++j){
            float a = cre[j][n], b = cim[j][n];
            r0x[j] = fmaf(a,u0, fmaf(b,v0, r0x[j]));
            r0y[j] = fmaf(a,s0, fmaf(b,q0, r0y[j]));
            r1x[j] = fmaf(a,u1, fmaf(b,v1, r1x[j]));
            r1y[j] = fmaf(a,s1, fmaf(b,q1, r1y[j]));
        }
        r0x[8] = fmaf(pr,u0, fmaf(-pi,v0, r0x[8]));
        r0y[8] = fmaf(pr,s0, fmaf(-pi,q0, r0y[8]));
        r1x[8] = fmaf(pr,u1, fmaf(-pi,v1, r1x[8]));
        r1y[8] = fmaf(pr,s1, fmaf(-pi,q1, r1y[8]));
    }

    float dt = dt_sh;
    #pragma unroll
    for (int j=0;j<9;++j){ r0x[j]*=dt; r0y[j]*=dt; r1x[j]*=dt; r1y[j]*=dt; }
    float drr = 1.0f + r1x[8], dii = r1y[8];
    float idn = frcp(drr*drr + dii*dii);
    float gx = (r0x[8]*drr + r0y[8]*dii)*idn;
    float gy = (r0y[8]*drr - r0x[8]*dii)*idn;
    float tfx = zt.z, tfy = zt.w;
    #pragma unroll
    for (int j=0;j<8;++j){
        float kr = r0x[j] - (gx*r1x[j] - gy*r1y[j]);
        float ki = r0y[j] - (gx*r1y[j] + gy*r1x[j]);
        KF[((size_t)((c0+j)*256+h))*1026 + l] = make_float2(kr*tfx - ki*tfy, kr*tfy + ki*tfx);
    }
}

// ---------------- radix-8 butterfly on registers (post-twiddle) ----------------
template<bool INV>
__device__ __forceinline__ void bfly8(float2 v[8]){
    float2 e0,e1,e2,e3,o0,o1,o2,o3;
    {   // DFT4 of v0,v2,v4,v6
        float t0x=v[0].x+v[4].x, t0y=v[0].y+v[4].y;
        float t1x=v[0].x-v[4].x, t1y=v[0].y-v[4].y;
        float t2x=v[2].x+v[6].x, t2y=v[2].y+v[6].y;
        float t3x=v[2].x-v[6].x, t3y=v[2].y-v[6].y;
        e0 = make_float2(t0x+t2x, t0y+t2y);
        e2 = make_float2(t0x-t2x, t0y-t2y);
        if (!INV){ e1 = make_float2(t1x+t3y, t1y-t3x); e3 = make_float2(t1x-t3y, t1y+t3x); }
        else     { e1 = make_float2(t1x-t3y, t1y+t3x); e3 = make_float2(t1x+t3y, t1y-t3x); }
    }
    {   // DFT4 of v1,v3,v5,v7
        float t0x=v[1].x+v[5].x, t0y=v[1].y+v[5].y;
        float t1x=v[1].x-v[5].x, t1y=v[1].y-v[5].y;
        float t2x=v[3].x+v[7].x, t2y=v[3].y+v[7].y;
        float t3x=v[3].x-v[7].x, t3y=v[3].y-v[7].y;
        o0 = make_float2(t0x+t2x, t0y+t2y);
        o2 = make_float2(t0x-t2x, t0y-t2y);
        if (!INV){ o1 = make_float2(t1x+t3y, t1y-t3x); o3 = make_float2(t1x-t3y, t1y+t3x); }
        else     { o1 = make_float2(t1x-t3y, t1y+t3x); o3 = make_float2(t1x+t3y, t1y-t3x); }
    }
    const float RC = 0.70710678118654752f;
    float2 w1o1, w2o2, w3o3;
    if (!INV){
        w1o1 = make_float2(RC*(o1.x+o1.y), RC*(o1.y-o1.x));    // (1-i)/sqrt2
        w2o2 = make_float2(o2.y, -o2.x);                       // -i
        w3o3 = make_float2(RC*(o3.y-o3.x), RC*(-o3.x-o3.y));   // -(1+i)/sqrt2
    } else {
        w1o1 = make_float2(RC*(o1.x-o1.y), RC*(o1.y+o1.x));    // (1+i)/sqrt2
        w2o2 = make_float2(-o2.y, o2.x);                       // i
        w3o3 = make_float2(RC*(-o3.x-o3.y), RC*(o3.x-o3.y));   // (-1+i)/sqrt2
    }
    v[0] = make_float2(e0.x+o0.x,   e0.y+o0.y);
    v[1] = make_float2(e1.x+w1o1.x, e1.y+w1o1.y);
    v[2] = make_float2(e2.x+w2o2.x, e2.y+w2o2.y);
    v[3] = make_float2(e3.x+w3o3.x, e3.y+w3o3.y);
    v[4] = make_float2(e0.x-o0.x,   e0.y-o0.y);
    v[5] = make_float2(e1.x-w1o1.x, e1.y-w1o1.y);
    v[6] = make_float2(e2.x-w2o2.x, e2.y-w2o2.y);
    v[7] = make_float2(e3.x-w3o3.x, e3.y-w3o3.y);
}

// ---------------- fft2048 = radix-4 (cross-wave) x 512-FFT (wave-local) ------
// 2048 = 4 groups x 512. Stage A: two stride-512 radix-4 butterflies in regs;
// post-twiddle; scatter to A[g][r]. One barrier. Then wave w runs the 512-pt
// FFT of group w alone: 3 radix-8 stages with only lgkmcnt fences. One final
// barrier. Output: bin 4s+g at B[gslot(g,s)].
template<bool INV>
__device__ __forceinline__ void fftR(float2 v[8], float2* __restrict__ A, float2* __restrict__ B){
    const int t = threadIdx.x;
    #pragma unroll
    for (int half=0; half<2; ++half){
        int r = t + half*256;
        float2 x0=v[half], x1=v[2+half], x2=v[4+half], x3=v[6+half];
        float t0x=x0.x+x2.x, t0y=x0.y+x2.y;
        float t1x=x0.x-x2.x, t1y=x0.y-x2.y;
        float t2x=x1.x+x3.x, t2y=x1.y+x3.y;
        float t3x=x1.x-x3.x, t3y=x1.y-x3.y;
        float2 y0 = make_float2(t0x+t2x, t0y+t2y);
        float2 y2 = make_float2(t0x-t2x, t0y-t2y);
        float2 y1, y3;
        if (!INV){ y1 = make_float2(t1x+t3y, t1y-t3x); y3 = make_float2(t1x-t3y, t1y+t3x); }
        else     { y1 = make_float2(t1x-t3y, t1y+t3x); y3 = make_float2(t1x+t3y, t1y-t3x); }
        float2 w1 = twid((float)r * (1.0f/2048.0f));
        if (INV) w1.y = -w1.y;
        float2 w2 = cmulf(w1,w1);
        float2 w3 = cmulf(w2,w1);
        A[gslot(0,r)] = y0;
        A[gslot(1,r)] = cmulf(y1,w1);
        A[gslot(2,r)] = cmulf(y2,w2);
        A[gslot(3,r)] = cmulf(y3,w3);
    }
    __syncthreads();
    const int w = t >> 6, l = t & 63;
    // ---- g1: NS=1, A -> B (wave-local) ----
    {
        float2 u[8];
        #pragma unroll
        for (int m=0;m<8;++m) u[m] = A[gslot(w, l + 64*m)];
        bfly8<INV>(u);
        #pragma unroll
        for (int q=0;q<8;++q) B[gslot(w, 8*l+q)] = u[q];
    }
    lds_fence();
    // ---- g2: NS=8, B -> A (wave-local) ----
    {
        float2 u[8];
        #pragma unroll
        for (int m=0;m<8;++m) u[m] = B[gslot(w, l + 64*m)];
        int jm = l & 7;
        float2 w1 = twid((float)jm * (1.0f/64.0f));
        if (INV) w1.y = -w1.y;
        float2 wc = w1;
        #pragma unroll
        for (int m=1;m<8;++m){ u[m] = cmulf(u[m], wc); if (m<7) wc = cmulf(wc, w1); }
        bfly8<INV>(u);
        int d = ((l - jm) << 3) + jm;
        #pragma unroll
        for (int q=0;q<8;++q) A[gslot(w, d + q*8)] = u[q];
    }
    lds_fence();
    // ---- g3: NS=64, A -> B (wave-local) ----
    {
        float2 u[8];
        #pragma unroll
        for (int m=0;m<8;++m) u[m] = A[gslot(w, l + 64*m)];
        float2 w1 = twid((float)l * (1.0f/512.0f));
        if (INV) w1.y = -w1.y;
        float2 wc = w1;
        #pragma unroll
        for (int m=1;m<8;++m){ u[m] = cmulf(u[m], wc); if (m<7) wc = cmulf(wc, w1); }
        bfly8<INV>(u);
        #pragma unroll
        for (int q=0;q<8;++q) B[gslot(w, l + q*64)] = u[q];
    }
    __syncthreads();
}

// ---------------- kernel C2: pd rows -> packed even/odd 4096-bin spectra ---------
__global__ __launch_bounds__(256,2) void kernC2(const float* __restrict__ pd,
                                                float2* __restrict__ PDE, float2* __restrict__ PDO){
    __shared__ float2 A[4*GS], Bb[4*GS];
    const int t = threadIdx.x;
    const int h = blockIdx.x;
    const float* p0 = pd + (size_t)h * 2048;
    const float* p1 = pd + (size_t)(256 + h) * 2048;
    float2 z[8], v[8];
    #pragma unroll
    for (int m=0;m<8;++m){
        int j = t + m*256;
        z[m] = make_float2(p0[j], p1[j]);
        v[m] = z[m];
    }
    fftR<false>(v, A, Bb);                    // bins in Bb (permuted layout)
    float2* oe = PDE + (size_t)h * 2048;
    #pragma unroll
    for (int m=0;m<8;++m){ int j = t + m*256; oe[j] = Bb[binslot(j)]; }
    #pragma unroll
    for (int m=0;m<8;++m){
        int j = t + m*256;
        v[m] = cmulf(twid((float)j * (1.0f/4096.0f)), z[m]);   // * e^{-2pi i j/4096}
    }
    fftR<false>(v, A, Bb);
    float2* oo = PDO + (size_t)h * 2048;
    #pragma unroll
    for (int m=0;m<8;++m){ int j = t + m*256; oo[j] = Bb[binslot(j)]; }
}

// ---------------- fused kernel F v10 ----------------
// Round-10 occupancy unlock: kernF was 2 blocks/CU (LDS 67.8KB) with VALU 44%,
// Occ 19.6% - 56% of cycles stalled with only 2 waves/SIMD to hide them.
//  (a) pdo_s staging DROPPED (-16KB LDS): pdo read exactly once per pair
//      (unpack); read po[j] from global there. The 8 same-h blocks (id stride
//      256 % 8 == 0) share one XCD -> row L2-hot after first touch. LDS ->
//      51.5KB -> 3 blocks/CU.
//  (b) grid y=8: 2 pairs (4 channels) per block, 2048 short blocks -> the
//      768-slot residency fills with fine granularity (no monolithic tail).
//  FFT engine + channel pairing byte-identical to round 8 (verified).
// Tripwires: WRITE>100MB => spill; VALU still ~44% at Occ ~30% => LDS-pipe
// bound -> next lever is single-buffer in-place 512-FFT.
__global__ __launch_bounds__(256,2) void kernF(const float2* __restrict__ KFb,
                                               const float2* __restrict__ PDE,
                                               const float2* __restrict__ PDO,
                                               const float* __restrict__ DCT,
                                               float* __restrict__ out){
    __shared__ float2 A[4*GS], Bb[4*GS];
    __shared__ float2 pde_s[2048];
    const int t = threadIdx.x;
    const int h = blockIdx.x;
    const int cq = blockIdx.y;                 // 0..7, 4 channels (2 pairs) each
    const float2* po = PDO + (size_t)h * 2048;
    {
        const float2* pe = PDE + (size_t)h * 2048;
        #pragma unroll
        for (int m=0;m<8;++m){
            int j = t + m*256;
            pde_s[j] = pe[j];
        }
    }
    float accr[8], acci[8];
    #pragma unroll
    for (int m=0;m<8;++m){ accr[m]=0.f; acci[m]=0.f; }
    __syncthreads();                            // pde_s visible to all

    #pragma unroll 1
    for (int pp=0; pp<2; ++pp){
        const int ca = cq*4 + pp*2;
        const float2* ra = KFb + (size_t)(ca*256+h)*1026;
        const float2* rb = KFb + (size_t)((ca+1)*256+h)*1026;

        // prefetch dct for both channels (consumed after FFTs; hides latency)
        float dcva[8], dcvb[8];
        {
            const float* dcta = DCT + (size_t)(h*32 + ca) * 2048;
            const float* dctb = dcta + 2048;
            #pragma unroll
            for (int m=0;m<8;++m){
                int j = t + m*256;
                dcva[m] = dcta[j] * (1.0f/4096.0f);
                dcvb[m] = dctb[j] * (1.0f/4096.0f);
            }
        }
        float2 v[8];

        // ---- Phase E, channel a: ifft(pde * Herm(kf_a)); accumulate ----
        #pragma unroll
        for (int m=0;m<8;++m){
            int j = t + m*256;
            float2 u;
            if (j <= 1024) u = ra[j];
            else { float2 w = ra[2048-j]; u = make_float2(w.x, -w.y); }  // Hermitian
            v[m] = cmulf(pde_s[j], u);
        }
        fftR<true>(v, A, Bb);
        #pragma unroll
        for (int m=0;m<8;++m){
            int j = t + m*256;
            float2 xe = Bb[binslot(j)];
            accr[m] = fmaf(xe.x, dcva[m], accr[m]);
            acci[m] = fmaf(xe.y, dcva[m], acci[m]);
        }
        // ---- Phase E, channel b ----
        #pragma unroll
        for (int m=0;m<8;++m){
            int j = t + m*256;
            float2 u;
            if (j <= 1024) u = rb[j];
            else { float2 w = rb[2048-j]; u = make_float2(w.x, -w.y); }
            v[m] = cmulf(pde_s[j], u);
        }
        fftR<true>(v, A, Bb);
        #pragma unroll
        for (int m=0;m<8;++m){
            int j = t + m*256;
            float2 xe = Bb[binslot(j)];
            accr[m] = fmaf(xe.x, dcvb[m], accr[m]);
            acci[m] = fmaf(xe.y, dcvb[m], acci[m]);
        }

        // ---- Phase O (paired): ifft(Herm_a + i*Herm_b) = 2048*(k_a + i*k_b) ----
        #pragma unroll
        for (int m=0;m<8;++m){
            int j = t + m*256;
            float2 va, vb;
            if (j <= 1024){ va = ra[j]; vb = rb[j]; }
            else {
                float2 u = ra[2048-j]; va = make_float2(u.x, -u.y);
                float2 w = rb[2048-j]; vb = make_float2(w.x, -w.y);
            }
            v[m] = make_float2(va.x - vb.y, va.y + vb.x);
        }
        fftR<true>(v, A, Bb);                  // packed k in Bb (sample n at binslot(n))
        // modulate (gather time-sample n = t+256m), feed Z-fft from regs
        #pragma unroll
        for (int m=0;m<8;++m){
            int j = t + m*256;
            float2 kk = Bb[binslot(j)];
            kk.x *= (1.0f/2048.0f); kk.y *= (1.0f/2048.0f);
            v[m] = cmulf(kk, twid((float)j * (1.0f/4096.0f)));   // * e^{-2pi i j/4096}
        }
        fftR<false>(v, A, Bb);                 // Z = K2odd_a + i*K2odd_b in Bb

        // unpack + products (cross reads of Bb, behind fftR's final sync)
        float2 pa[8], sb[8];
        #pragma unroll
        for (int m=0;m<8;++m){
            int j  = t + m*256;
            float2 z  = Bb[binslot(j)];
            float2 zm = Bb[binslot(2047 - j)];
            float2 Ka = make_float2(0.5f*(z.x + zm.x), 0.5f*(z.y - zm.y));
            float2 Kb = make_float2(0.5f*(z.y + zm.y), 0.5f*(zm.x - z.x));
            float2 pov = po[j];                  // global (L2-hot row, read 1x/pair)
            pa[m] = cmulf(pov, Ka);
            sb[m] = cmulf(pov, Kb);
        }
        // ifft channel a
        fftR<true>(pa, A, Bb);
        #pragma unroll
        for (int m=0;m<8;++m){
            int j = t + m*256;
            float2 w = twid((float)j * (1.0f/4096.0f));
            float2 ee = make_float2(w.x, -w.y);      // e^{+2pi i j/4096}
            float2 rot = cmulf(ee, Bb[binslot(j)]);
            accr[m] = fmaf(rot.x, dcva[m], accr[m]);
            acci[m] = fmaf(rot.y, dcva[m], acci[m]);
        }
        // ifft channel b from held regs
        fftR<true>(sb, A, Bb);
        #pragma unroll
        for (int m=0;m<8;++m){
            int j = t + m*256;
            float2 w = twid((float)j * (1.0f/4096.0f));
            float2 ee = make_float2(w.x, -w.y);
            float2 rot = cmulf(ee, Bb[binslot(j)]);
            accr[m] = fmaf(rot.x, dcvb[m], accr[m]);
            acci[m] = fmaf(rot.y, dcvb[m], acci[m]);
        }
    }
    #pragma unroll
    for (int m=0;m<8;++m){
        int j = t + m*256;
        atomicAdd(&out[((size_t)h)*2048 + j],       accr[m]);   // batch 0 (Re)
        atomicAdd(&out[((size_t)(256+h))*2048 + j], acci[m]);   // batch 1 (Im)
    }
}

extern "C" void kernel_launch(void* const* d_in, const int* in_sizes, int n_in,
                              void* d_out, int out_size, void* d_ws, size_t ws_size,
                              hipStream_t stream) {
    const float* log_dt = (const float*)d_in[0];
    const float* B_ri   = (const float*)d_in[1];
    const float* P_ri   = (const float*)d_in[2];
    const float* C_ri   = (const float*)d_in[3];
    const float* ivw    = (const float*)d_in[4];
    const float* wimag  = (const float*)d_in[5];
    const float* dC     = (const float*)d_in[6];
    const float* pd     = (const float*)d_in[7];

    char* ws = (char*)d_ws;
    float4* ZT  = (float4*)(ws + OFF_ZT);
    float2* KF  = (float2*)(ws + OFF_KF);
    float2* PDE = (float2*)(ws + OFF_PDF);
    float2* PDO = (float2*)(ws + OFF_PDF + 256*2048*sizeof(float2));
    float*  DCT = (float*) (ws + OFF_DCT);
    float* out = (float*)d_out;

    hipMemsetAsync(out, 0, (size_t)out_size * sizeof(float), stream);
    initk<<<5, 256, 0, stream>>>(ZT);
    transpose_dC<<<dim3(256,64), dim3(32,8), 0, stream>>>(dC, DCT);
    cauchy_k<<<dim3(5,256,4), 256, 0, stream>>>(log_dt, B_ri, P_ri, C_ri, ivw, wimag, ZT, KF);
    kernC2<<<256, 256, 0, stream>>>(pd, PDE, PDO);
    kernF<<<dim3(256,8), 256, 0, stream>>>((const float2*)KF, PDE, PDO, DCT, out);
}

// Round 11
// 378.000 us; speedup vs baseline: 1.0703x; 1.0703x over previous
//
#include <hip/hip_runtime.h>
#include <math.h>

// Problem constants (reference: H=256, N=32, S=256, R=1, CCH=32, L=2048, B=2)
#define LF   1025     // L/2+1

// ---- workspace layout (bytes) ----
#define OFF_ZT   65536
#define OFF_KF   131072
#define OFF_PDF  67371008
#define OFF_DCT  84148224

__device__ __forceinline__ float2 cmulf(float2 a, float2 b){
    return make_float2(a.x*b.x - a.y*b.y, a.x*b.y + a.y*b.x);
}

// e^{-2 pi i r}, 0 <= r < 1 (exact dyadic). v_sin/v_cos take REVOLUTIONS on
// gfx9xx -> no table, no gather, no range reduction needed.
__device__ __forceinline__ float2 twid(float r){
    float s, c;
    asm("v_sin_f32 %0, %1" : "=v"(s) : "v"(r));
    asm("v_cos_f32 %0, %1" : "=v"(c) : "v"(r));
    return make_float2(c, -s);
}
// fast reciprocal (~1 ulp) - tolerance is 7.8e-3, plenty of margin
__device__ __forceinline__ float frcp(float x){
    float y; asm("v_rcp_f32 %0, %1" : "=v"(y) : "v"(x)); return y;
}
// own-wave LDS ordering fence
__device__ __forceinline__ void lds_fence(){
    asm volatile("s_waitcnt lgkmcnt(0)" ::: "memory");
}

// FFT buffers: 4 groups x 512, group stride 548 + intra-group pad every 16.
#define GS 548
__device__ __forceinline__ int gslot(int g, int s){ return g*GS + s + (s >> 4); }
// LDS-out FFT: bin j lives at gslot(j&3, j>>2)
__device__ __forceinline__ int binslot(int j){ return gslot(j & 3, j >> 2); }

// ---------------- init: bilinear nodes (fp64 once) ----------------
__global__ void initk(float4* __restrict__ ZT){
    int i = blockIdx.x*256 + threadIdx.x;
    if (i < LF){
        double th = (-2.0*M_PI) * (double)i / 2048.0;
        double cr = cos(th), ci = sin(th);
        double ar = 1.0 + cr, ai = ci;              // 1+w
        double den = ar*ar + ai*ai;
        double nr = 1.0 - cr, ni = -ci;             // 1-w
        double zr = 2.0*(nr*ar + ni*ai)/den;        // z = 2(1-w)/(1+w)
        double zi = 2.0*(ni*ar - nr*ai)/den;
        ZT[i] = make_float4((float)zr, (float)zi, (float)(2.0*ar/den), (float)(-2.0*ai/den));
    }
}

// ---------------- dC (l, h, c) -> DCT (h*32+c, perm(l)) ----------------
// Round-11: DCT stored PERMUTED so kernF's register-handoff consumers read it
// coalesced: value for time-index l stored at position
//   p(l) = (l & ~255) | ((l&255)>>2) | ((l&3)<<6)
// => kernF load at linear position t+256q yields dct[4*(t&63)+(t>>6)+256q].
__global__ void transpose_dC(const float* __restrict__ dC, float* __restrict__ DCT){
    __shared__ float tile[32][33];
    int hc0 = blockIdx.x*32;
    int l0  = blockIdx.y*32;
    int tx = threadIdx.x;
    for (int i = threadIdx.y; i < 32; i += 8)
        tile[i][tx] = dC[(size_t)(l0+i)*8192 + hc0 + tx];
    __syncthreads();
    for (int i = threadIdx.y; i < 32; i += 8){
        int l = l0 + tx;
        int p = (l & ~255) | ((l & 255) >> 2) | ((l & 3) << 6);
        DCT[(size_t)(hc0+i)*2048 + p] = tile[tx][i];
    }
}

// ---------------- Cauchy + Woodbury -> k_f (round-8 form, verified best) ------
__global__ __launch_bounds__(256) void cauchy_k(
                         const float* __restrict__ log_dt, const float* __restrict__ B_ri,
                         const float* __restrict__ P_ri, const float* __restrict__ C_ri,
                         const float* __restrict__ ivw, const float* __restrict__ wimag,
                         const float4* __restrict__ ZT, float2* __restrict__ KF)
{
    const int h  = blockIdx.y;
    const int c0 = blockIdx.z * 8;
    const int l  = blockIdx.x*256 + (int)threadIdx.x;
    __shared__ float wre[32], wim[32], bre[32], bim[32], ppre[32], ppim[32];
    __shared__ float cre[8][32], cim[8][32];
    __shared__ float dt_sh;
    if (threadIdx.x < 32){
        int n = threadIdx.x;
        float dt = expf(log_dt[h]);
        wre[n] = -expf(ivw[h*32+n]) * dt;
        wim[n] = wimag[h*32+n] * dt;
        bre[n] = B_ri[(h*32+n)*2+0];
        bim[n] = B_ri[(h*32+n)*2+1];
        ppre[n] = P_ri[(h*32+n)*2+0];
        ppim[n] = P_ri[(h*32+n)*2+1];
        if (n == 0) dt_sh = dt;
    }
    {
        int i = threadIdx.x;
        int cc = i >> 5, n = i & 31;
        size_t base = (((size_t)(c0+cc)*256 + h)*32 + n)*2;
        cre[cc][n] = C_ri[base+0];
        cim[cc][n] = C_ri[base+1];
    }
    __syncthreads();
    if (l >= LF) return;

    float4 zt = ZT[l];
    const float zx = zt.x, zy = zt.y;
    float r0x[9], r0y[9], r1x[9], r1y[9];
    #pragma unroll
    for (int j=0;j<9;++j){ r0x[j]=0.f; r0y[j]=0.f; r1x[j]=0.f; r1y[j]=0.f; }

    #pragma unroll 1
    for (int n=0; n<32; ++n){
        float wr = wre[n], wi = wim[n];
        float dx = zx - wr;
        float dy = zy - wi;
        float ey = zy + wi;
        float ip = frcp(dx*dx + dy*dy);
        float im = frcp(dx*dx + ey*ey);
        float cpx = dx*ip, cpy = -dy*ip;
        float cmx = dx*im, cmy = -ey*im;
        float br = bre[n], bi = bim[n];
        float t0x = br*cpx - bi*cpy, t0y = br*cpy + bi*cpx;
        float t1x = br*cmx + bi*cmy, t1y = br*cmy - bi*cmx;
        float pr = ppre[n], pi = ppim[n];
        float t2x = pr*cpx - pi*cpy, t2y = pr*cpy + pi*cpx;
        float t3x = pr*cmx + pi*cmy, t3y = pr*cmy - pi*cmx;
        float u0 = t0x+t1x, v0 = t1y-t0y, s0 = t0y+t1y, q0 = t0x-t1x;
        float u1 = t2x+t3x, v1 = t3y-t2y, s1 = t2y+t3y, q1 = t2x-t3x;
        #pragma unroll
        for (int j=0;j<8;++j){
            float a = cre[j][n], b = cim[j][n];
            r0x[j] = fmaf(a,u0, fmaf(b,v0, r0x[j]));
            r0y[j] = fmaf(a,s0, fmaf(b,q0, r0y[j]));
            r1x[j] = fmaf(a,u1, fmaf(b,v1, r1x[j]));
            r1y[j] = fmaf(a,s1, fmaf(b,q1, r1y[j]));
        }
        r0x[8] = fmaf(pr,u0, fmaf(-pi,v0, r0x[8]));
        r0y[8] = fmaf(pr,s0, fmaf(-pi,q0, r0y[8]));
        r1x[8] = fmaf(pr,u1, fmaf(-pi,v1, r1x[8]));
        r1y[8] = fmaf(pr,s1, fmaf(-pi,q1, r1y[8]));
    }

    float dt = dt_sh;
    #pragma unroll
    for (int j=0;j<9;++j){ r0x[j]*=dt; r0y[j]*=dt; r1x[j]*=dt; r1y[j]*=dt; }
    float drr = 1.0f + r1x[8], dii = r1y[8];
    float idn = frcp(drr*drr + dii*dii);
    float gx = (r0x[8]*drr + r0y[8]*dii)*idn;
    float gy = (r0y[8]*drr - r0x[8]*dii)*idn;
    float tfx = zt.z, tfy = zt.w;
    #pragma unroll
    for (int j=0;j<8;++j){
        float kr = r0x[j] - (gx*r1x[j] - gy*r1y[j]);
        float ki = r0y[j] - (gx*r1y[j] + gy*r1x[j]);
        KF[((size_t)((c0+j)*256+h))*1026 + l] = make_float2(kr*tfx - ki*tfy, kr*tfy + ki*tfx);
    }
}

// ---------------- radix-8 butterfly on registers (post-twiddle) ----------------
template<bool INV>
__device__ __forceinline__ void bfly8(float2 v[8]){
    float2 e0,e1,e2,e3,o0,o1,o2,o3;
    {   // DFT4 of v0,v2,v4,v6
        float t0x=v[0].x+v[4].x, t0y=v[0].y+v[4].y;
        float t1x=v[0].x-v[4].x, t1y=v[0].y-v[4].y;
        float t2x=v[2].x+v[6].x, t2y=v[2].y+v[6].y;
        float t3x=v[2].x-v[6].x, t3y=v[2].y-v[6].y;
        e0 = make_float2(t0x+t2x, t0y+t2y);
        e2 = make_float2(t0x-t2x, t0y-t2y);
        if (!INV){ e1 = make_float2(t1x+t3y, t1y-t3x); e3 = make_float2(t1x-t3y, t1y+t3x); }
        else     { e1 = make_float2(t1x-t3y, t1y+t3x); e3 = make_float2(t1x+t3y, t1y-t3x); }
    }
    {   // DFT4 of v1,v3,v5,v7
        float t0x=v[1].x+v[5].x, t0y=v[1].y+v[5].y;
        float t1x=v[1].x-v[5].x, t1y=v[1].y-v[5].y;
        float t2x=v[3].x+v[7].x, t2y=v[3].y+v[7].y;
        float t3x=v[3].x-v[7].x, t3y=v[3].y-v[7].y;
        o0 = make_float2(t0x+t2x, t0y+t2y);
        o2 = make_float2(t0x-t2x, t0y-t2y);
        if (!INV){ o1 = make_float2(t1x+t3y, t1y-t3x); o3 = make_float2(t1x-t3y, t1y+t3x); }
        else     { o1 = make_float2(t1x-t3y, t1y+t3x); o3 = make_float2(t1x+t3y, t1y-t3x); }
    }
    const float RC = 0.70710678118654752f;
    float2 w1o1, w2o2, w3o3;
    if (!INV){
        w1o1 = make_float2(RC*(o1.x+o1.y), RC*(o1.y-o1.x));    // (1-i)/sqrt2
        w2o2 = make_float2(o2.y, -o2.x);                       // -i
        w3o3 = make_float2(RC*(o3.y-o3.x), RC*(-o3.x-o3.y));   // -(1+i)/sqrt2
    } else {
        w1o1 = make_float2(RC*(o1.x-o1.y), RC*(o1.y+o1.x));    // (1+i)/sqrt2
        w2o2 = make_float2(-o2.y, o2.x);                       // i
        w3o3 = make_float2(RC*(-o3.x-o3.y), RC*(o3.x-o3.y));   // (-1+i)/sqrt2
    }
    v[0] = make_float2(e0.x+o0.x,   e0.y+o0.y);
    v[1] = make_float2(e1.x+w1o1.x, e1.y+w1o1.y);
    v[2] = make_float2(e2.x+w2o2.x, e2.y+w2o2.y);
    v[3] = make_float2(e3.x+w3o3.x, e3.y+w3o3.y);
    v[4] = make_float2(e0.x-o0.x,   e0.y-o0.y);
    v[5] = make_float2(e1.x-w1o1.x, e1.y-w1o1.y);
    v[6] = make_float2(e2.x-w2o2.x, e2.y-w2o2.y);
    v[7] = make_float2(e3.x-w3o3.x, e3.y-w3o3.y);
}

// ---------------- fft2048 = radix-4 (cross-wave) x 512-FFT (wave-local) ------
// Round-11 generalization of the verified round-8 engine:
//  - input element base r0 is now a per-thread PARAMETER (thread holds elements
//    r0+256m; {r0} must be a bijection on [0,256)). r0=t for natural-order
//    inputs; r0=jbase for register-chained inputs.
//  - REGOUT: g3's result stays in registers (v[q] = bin jq = 4*(t&63)+(t>>6)
//    +256q), skipping 8 ds_write + 8 ds_read + the glue load-use chain. Used
//    for the 5 of 6 FFTs per pair with pointwise consumers; the Z-fft (needs
//    the 2047-j cross-gather) keeps LDS output (bin j at binslot(j)).
// Barriers unchanged (stage A's cross-wave scatter needs both).
template<bool INV, bool REGOUT>
__device__ __forceinline__ void fftR(float2 v[8], int r0, float2* __restrict__ A, float2* __restrict__ B){
    const int t = threadIdx.x;
    #pragma unroll
    for (int half=0; half<2; ++half){
        int r = r0 + half*256;
        float2 x0=v[half], x1=v[2+half], x2=v[4+half], x3=v[6+half];
        float t0x=x0.x+x2.x, t0y=x0.y+x2.y;
        float t1x=x0.x-x2.x, t1y=x0.y-x2.y;
        float t2x=x1.x+x3.x, t2y=x1.y+x3.y;
        float t3x=x1.x-x3.x, t3y=x1.y-x3.y;
        float2 y0 = make_float2(t0x+t2x, t0y+t2y);
        float2 y2 = make_float2(t0x-t2x, t0y-t2y);
        float2 y1, y3;
        if (!INV){ y1 = make_float2(t1x+t3y, t1y-t3x); y3 = make_float2(t1x-t3y, t1y+t3x); }
        else     { y1 = make_float2(t1x-t3y, t1y+t3x); y3 = make_float2(t1x+t3y, t1y-t3x); }
        float2 w1 = twid((float)r * (1.0f/2048.0f));
        if (INV) w1.y = -w1.y;
        float2 w2 = cmulf(w1,w1);
        float2 w3 = cmulf(w2,w1);
        A[gslot(0,r)] = y0;
        A[gslot(1,r)] = cmulf(y1,w1);
        A[gslot(2,r)] = cmulf(y2,w2);
        A[gslot(3,r)] = cmulf(y3,w3);
    }
    __syncthreads();
    const int w = t >> 6, l = t & 63;
    // ---- g1: NS=1, A -> B (wave-local) ----
    {
        float2 u[8];
        #pragma unroll
        for (int m=0;m<8;++m) u[m] = A[gslot(w, l + 64*m)];
        bfly8<INV>(u);
        #pragma unroll
        for (int q=0;q<8;++q) B[gslot(w, 8*l+q)] = u[q];
    }
    lds_fence();
    // ---- g2: NS=8, B -> A (wave-local) ----
    {
        float2 u[8];
        #pragma unroll
        for (int m=0;m<8;++m) u[m] = B[gslot(w, l + 64*m)];
        int jm = l & 7;
        float2 w1 = twid((float)jm * (1.0f/64.0f));
        if (INV) w1.y = -w1.y;
        float2 wc = w1;
        #pragma unroll
        for (int m=1;m<8;++m){ u[m] = cmulf(u[m], wc); if (m<7) wc = cmulf(wc, w1); }
        bfly8<INV>(u);
        int d = ((l - jm) << 3) + jm;
        #pragma unroll
        for (int q=0;q<8;++q) A[gslot(w, d + q*8)] = u[q];
    }
    lds_fence();
    // ---- g3: NS=64, A -> regs or B (wave-local) ----
    {
        float2 u[8];
        #pragma unroll
        for (int m=0;m<8;++m) u[m] = A[gslot(w, l + 64*m)];
        float2 w1 = twid((float)l * (1.0f/512.0f));
        if (INV) w1.y = -w1.y;
        float2 wc = w1;
        #pragma unroll
        for (int m=1;m<8;++m){ u[m] = cmulf(u[m], wc); if (m<7) wc = cmulf(wc, w1); }
        bfly8<INV>(u);
        if constexpr (REGOUT){
            #pragma unroll
            for (int q=0;q<8;++q) v[q] = u[q];      // bin 4l + w + 256q
        } else {
            #pragma unroll
            for (int q=0;q<8;++q) B[gslot(w, l + q*64)] = u[q];
        }
    }
    __syncthreads();
}

// ---------------- kernel C2: pd rows -> packed even/odd 4096-bin spectra ---------
__global__ __launch_bounds__(256,2) void kernC2(const float* __restrict__ pd,
                                                float2* __restrict__ PDE, float2* __restrict__ PDO){
    __shared__ float2 A[4*GS], Bb[4*GS];
    const int t = threadIdx.x;
    const int h = blockIdx.x;
    const float* p0 = pd + (size_t)h * 2048;
    const float* p1 = pd + (size_t)(256 + h) * 2048;
    float2 z[8], v[8];
    #pragma unroll
    for (int m=0;m<8;++m){
        int j = t + m*256;
        z[m] = make_float2(p0[j], p1[j]);
        v[m] = z[m];
    }
    fftR<false,false>(v, t, A, Bb);           // bins in Bb (binslot layout)
    float2* oe = PDE + (size_t)h * 2048;
    #pragma unroll
    for (int m=0;m<8;++m){ int j = t + m*256; oe[j] = Bb[binslot(j)]; }
    #pragma unroll
    for (int m=0;m<8;++m){
        int j = t + m*256;
        v[m] = cmulf(twid((float)j * (1.0f/4096.0f)), z[m]);   // * e^{-2pi i j/4096}
    }
    fftR<false,false>(v, t, A, Bb);
    float2* oo = PDO + (size_t)h * 2048;
    #pragma unroll
    for (int m=0;m<8;++m){ int j = t + m*256; oo[j] = Bb[binslot(j)]; }
}

// ---------------- fused kernel F v11 ----------------
// Base = round-8 verified best (grid y=2, pde_s+pdo_s staged, 67.8KB LDS,
// launch_bounds(256,2)=128 VGPR clean, channel pairing, wave-local FFT).
// Round-11 change: register handoff out of g3 (REGOUT) for the 5 pointwise-
// consumed FFTs; consumers remapped to jq = jbase + 256q, jbase =
// 4*(t&63)+(t>>6). DCT is pre-permuted so dct loads stay coalesced; out
// atomics scatter at jq (stride-4, negligible on 4MB).
__global__ __launch_bounds__(256,2) void kernF(const float2* __restrict__ KFb,
                                               const float2* __restrict__ PDE,
                                               const float2* __restrict__ PDO,
                                               const float* __restrict__ DCT,
                                               float* __restrict__ out){
    __shared__ float2 A[4*GS], Bb[4*GS];
    __shared__ float2 pde_s[2048], pdo_s[2048];
    const int t = threadIdx.x;
    const int h = blockIdx.x;
    const int cq = blockIdx.y;                 // 0..1, 16 channels (8 pairs) each
    const int jbase = ((t & 63) << 2) | (t >> 6);
    {
        const float2* pe = PDE + (size_t)h * 2048;
        const float2* po = PDO + (size_t)h * 2048;
        #pragma unroll
        for (int m=0;m<8;++m){
            int j = t + m*256;
            pde_s[j] = pe[j];
            pdo_s[j] = po[j];
        }
    }
    float accr[8], acci[8];
    #pragma unroll
    for (int m=0;m<8;++m){ accr[m]=0.f; acci[m]=0.f; }
    __syncthreads();                            // pde_s/pdo_s visible to all

    #pragma unroll 1
    for (int pp=0; pp<8; ++pp){
        const int ca = cq*16 + pp*2;
        const float2* ra = KFb + (size_t)(ca*256+h)*1026;
        const float2* rb = KFb + (size_t)((ca+1)*256+h)*1026;

        // prefetch PERMUTED dct: linear load at t+256m yields dct[jbase+256m]
        float dcva[8], dcvb[8];
        {
            const float* dcta = DCT + (size_t)(h*32 + ca) * 2048;
            const float* dctb = dcta + 2048;
            #pragma unroll
            for (int m=0;m<8;++m){
                int j = t + m*256;
                dcva[m] = dcta[j] * (1.0f/4096.0f);
                dcvb[m] = dctb[j] * (1.0f/4096.0f);
            }
        }
        float2 v[8];

        // ---- Phase E, channel a: ifft(pde * Herm(kf_a)); reg-consume ----
        #pragma unroll
        for (int m=0;m<8;++m){
            int j = t + m*256;
            float2 u;
            if (j <= 1024) u = ra[j];
            else { float2 w = ra[2048-j]; u = make_float2(w.x, -w.y); }  // Hermitian
            v[m] = cmulf(pde_s[j], u);
        }
        fftR<true,true>(v, t, A, Bb);          // v[m] = x_e at sample jbase+256m
        #pragma unroll
        for (int m=0;m<8;++m){
            accr[m] = fmaf(v[m].x, dcva[m], accr[m]);
            acci[m] = fmaf(v[m].y, dcva[m], acci[m]);
        }
        // ---- Phase E, channel b ----
        #pragma unroll
        for (int m=0;m<8;++m){
            int j = t + m*256;
            float2 u;
            if (j <= 1024) u = rb[j];
            else { float2 w = rb[2048-j]; u = make_float2(w.x, -w.y); }
            v[m] = cmulf(pde_s[j], u);
        }
        fftR<true,true>(v, t, A, Bb);
        #pragma unroll
        for (int m=0;m<8;++m){
            accr[m] = fmaf(v[m].x, dcvb[m], accr[m]);
            acci[m] = fmaf(v[m].y, dcvb[m], acci[m]);
        }

        // ---- Phase O (paired): ifft(Herm_a + i*Herm_b) = 2048*(k_a + i*k_b) ----
        #pragma unroll
        for (int m=0;m<8;++m){
            int j = t + m*256;
            float2 va, vb;
            if (j <= 1024){ va = ra[j]; vb = rb[j]; }
            else {
                float2 u = ra[2048-j]; va = make_float2(u.x, -u.y);
                float2 w = rb[2048-j]; vb = make_float2(w.x, -w.y);
            }
            v[m] = make_float2(va.x - vb.y, va.y + vb.x);
        }
        fftR<true,true>(v, t, A, Bb);          // v[m] = packed k sample jbase+256m (x2048)
        // modulate in regs: sample n = jbase+256m, * e^{-2pi i n/4096}
        #pragma unroll
        for (int m=0;m<8;++m){
            float2 kk = v[m];
            kk.x *= (1.0f/2048.0f); kk.y *= (1.0f/2048.0f);
            v[m] = cmulf(kk, twid((float)(jbase + 256*m) * (1.0f/4096.0f)));
        }
        fftR<false,false>(v, jbase, A, Bb);    // Z in Bb at binslot (needs 2047-j gather)

        // unpack + products (cross reads of Bb, behind fftR's final sync)
        float2 pa[8], sb[8];
        #pragma unroll
        for (int m=0;m<8;++m){
            int j  = t + m*256;
            float2 z  = Bb[binslot(j)];
            float2 zm = Bb[binslot(2047 - j)];
            float2 Ka = make_float2(0.5f*(z.x + zm.x), 0.5f*(z.y - zm.y));
            float2 Kb = make_float2(0.5f*(z.y + zm.y), 0.5f*(zm.x - z.x));
            float2 pov = pdo_s[j];
            pa[m] = cmulf(pov, Ka);
            sb[m] = cmulf(pov, Kb);
        }
        // ifft channel a -> regs; rotate by e^{+2pi i jq/4096}; accumulate
        fftR<true,true>(pa, t, A, Bb);
        #pragma unroll
        for (int m=0;m<8;++m){
            float2 w = twid((float)(jbase + 256*m) * (1.0f/4096.0f));
            float2 ee = make_float2(w.x, -w.y);
            float2 rot = cmulf(ee, pa[m]);
            accr[m] = fmaf(rot.x, dcva[m], accr[m]);
            acci[m] = fmaf(rot.y, dcva[m], acci[m]);
        }
        // ifft channel b -> regs
        fftR<true,true>(sb, t, A, Bb);
        #pragma unroll
        for (int m=0;m<8;++m){
            float2 w = twid((float)(jbase + 256*m) * (1.0f/4096.0f));
            float2 ee = make_float2(w.x, -w.y);
            float2 rot = cmulf(ee, sb[m]);
            accr[m] = fmaf(rot.x, dcvb[m], accr[m]);
            acci[m] = fmaf(rot.y, dcvb[m], acci[m]);
        }
    }
    #pragma unroll
    for (int m=0;m<8;++m){
        int jq = jbase + 256*m;
        atomicAdd(&out[((size_t)h)*2048 + jq],       accr[m]);   // batch 0 (Re)
        atomicAdd(&out[((size_t)(256+h))*2048 + jq], acci[m]);   // batch 1 (Im)
    }
}

extern "C" void kernel_launch(void* const* d_in, const int* in_sizes, int n_in,
                              void* d_out, int out_size, void* d_ws, size_t ws_size,
                              hipStream_t stream) {
    const float* log_dt = (const float*)d_in[0];
    const float* B_ri   = (const float*)d_in[1];
    const float* P_ri   = (const float*)d_in[2];
    const float* C_ri   = (const float*)d_in[3];
    const float* ivw    = (const float*)d_in[4];
    const float* wimag  = (const float*)d_in[5];
    const float* dC     = (const float*)d_in[6];
    const float* pd     = (const float*)d_in[7];

    char* ws = (char*)d_ws;
    float4* ZT  = (float4*)(ws + OFF_ZT);
    float2* KF  = (float2*)(ws + OFF_KF);
    float2* PDE = (float2*)(ws + OFF_PDF);
    float2* PDO = (float2*)(ws + OFF_PDF + 256*2048*sizeof(float2));
    float*  DCT = (float*) (ws + OFF_DCT);
    float* out = (float*)d_out;

    hipMemsetAsync(out, 0, (size_t)out_size * sizeof(float), stream);
    initk<<<5, 256, 0, stream>>>(ZT);
    transpose_dC<<<dim3(256,64), dim3(32,8), 0, stream>>>(dC, DCT);
    cauchy_k<<<dim3(5,256,4), 256, 0, stream>>>(log_dt, B_ri, P_ri, C_ri, ivw, wimag, ZT, KF);
    kernC2<<<256, 256, 0, stream>>>(pd, PDE, PDO);
    kernF<<<dim3(256,2), 256, 0, stream>>>((const float2*)KF, PDE, PDO, DCT, out);
}

// Round 12
// 364.006 us; speedup vs baseline: 1.1115x; 1.0384x over previous
//
#include <hip/hip_runtime.h>
#include <math.h>

// Problem constants (reference: H=256, N=32, S=256, R=1, CCH=32, L=2048, B=2)
#define LF   1025     // L/2+1

// ---- workspace layout (bytes) ----
#define OFF_ZT   65536
#define OFF_KF   131072
#define OFF_PDF  67371008
#define OFF_DCT  84148224

__device__ __forceinline__ float2 cmulf(float2 a, float2 b){
    return make_float2(a.x*b.x - a.y*b.y, a.x*b.y + a.y*b.x);
}

// e^{-2 pi i r}, 0 <= r < 1 (exact dyadic). v_sin/v_cos take REVOLUTIONS on
// gfx9xx -> no table, no gather, no range reduction needed.
__device__ __forceinline__ float2 twid(float r){
    float s, c;
    asm("v_sin_f32 %0, %1" : "=v"(s) : "v"(r));
    asm("v_cos_f32 %0, %1" : "=v"(c) : "v"(r));
    return make_float2(c, -s);
}
// fast reciprocal (~1 ulp) - tolerance is 7.8e-3, plenty of margin
__device__ __forceinline__ float frcp(float x){
    float y; asm("v_rcp_f32 %0, %1" : "=v"(y) : "v"(x)); return y;
}
// own-wave LDS ordering fence
__device__ __forceinline__ void lds_fence(){
    asm volatile("s_waitcnt lgkmcnt(0)" ::: "memory");
}

// FFT buffers: 4 groups x 512, group stride 548 + intra-group pad every 16.
#define GS 548
__device__ __forceinline__ int gslot(int g, int s){ return g*GS + s + (s >> 4); }
// LDS-out FFT: bin j lives at gslot(j&3, j>>2)
__device__ __forceinline__ int binslot(int j){ return gslot(j & 3, j >> 2); }

// ---------------- init: bilinear nodes (fp64 once) ----------------
__global__ void initk(float4* __restrict__ ZT){
    int i = blockIdx.x*256 + threadIdx.x;
    if (i < LF){
        double th = (-2.0*M_PI) * (double)i / 2048.0;
        double cr = cos(th), ci = sin(th);
        double ar = 1.0 + cr, ai = ci;              // 1+w
        double den = ar*ar + ai*ai;
        double nr = 1.0 - cr, ni = -ci;             // 1-w
        double zr = 2.0*(nr*ar + ni*ai)/den;        // z = 2(1-w)/(1+w)
        double zi = 2.0*(ni*ar - nr*ai)/den;
        ZT[i] = make_float4((float)zr, (float)zi, (float)(2.0*ar/den), (float)(-2.0*ai/den));
    }
}

// ---------------- dC (l, h, c) -> DCT (h*32+c, perm(l)) ----------------
// Permutation (verified r11): value for time-index l stored at
//   p(l) = (l & ~255) | ((l&255)>>2) | ((l&3)<<6)
// so kernF's linear load at t+256q yields dct[jbase+256q], jbase=4*(t&63)+(t>>6).
// Round-12: r11 wrote DCT at p(l) with consecutive tx -> stride-64 scatter
// (uncoalesced 64MB, ~+13us). Now the WRITE loop iterates output index po
// linearly (coalesced) and gathers l = ((po&63)<<2)|(po>>6) from the LDS tile.
// Block: 32 hc x 256 l tile (33KB LDS); grid (256, 8).
__global__ __launch_bounds__(256) void transpose_dC(const float* __restrict__ dC, float* __restrict__ DCT){
    __shared__ float tile[32][260];    // [hc_local][l_local], stride 260 (pad)
    int hc0 = blockIdx.x*32;
    int l0  = blockIdx.y*256;
    int tx = threadIdx.x;              // 0..31
    int ty = threadIdx.y;              // 0..7
    for (int li = ty; li < 256; li += 8)
        tile[tx][li] = dC[(size_t)(l0+li)*8192 + hc0 + tx];    // coalesced in hc
    __syncthreads();
    for (int i = ty; i < 32; i += 8){
        #pragma unroll
        for (int pk = 0; pk < 256; pk += 32){
            int po = pk + tx;
            int ll = ((po & 63) << 2) | (po >> 6);
            DCT[(size_t)(hc0+i)*2048 + l0 + po] = tile[i][ll]; // coalesced in po
        }
    }
}

// ---------------- Cauchy + Woodbury -> k_f ----------------
// Round-12: LDS operand arrays packed as float2 (w, B, P, C) -> 11 ds_read_b64
// per pole instead of 22 ds_read_b32 (halves LDS issue on the hot loop).
// z=4 structure kept (r9 proved the 32-channel merge loses to occupancy).
// launch_bounds(256,2) pins the known-good 128-VGPR cap (natural ~90).
__global__ __launch_bounds__(256,2) void cauchy_k(
                         const float* __restrict__ log_dt, const float* __restrict__ B_ri,
                         const float* __restrict__ P_ri, const float* __restrict__ C_ri,
                         const float* __restrict__ ivw, const float* __restrict__ wimag,
                         const float4* __restrict__ ZT, float2* __restrict__ KF)
{
    const int h  = blockIdx.y;
    const int c0 = blockIdx.z * 8;
    const int l  = blockIdx.x*256 + (int)threadIdx.x;
    __shared__ float2 wv[32], bv[32], pv[32];
    __shared__ float2 cc[8][32];
    __shared__ float dt_sh;
    if (threadIdx.x < 32){
        int n = threadIdx.x;
        float dt = expf(log_dt[h]);
        wv[n] = make_float2(-expf(ivw[h*32+n]) * dt, wimag[h*32+n] * dt);
        bv[n] = make_float2(B_ri[(h*32+n)*2+0], B_ri[(h*32+n)*2+1]);
        pv[n] = make_float2(P_ri[(h*32+n)*2+0], P_ri[(h*32+n)*2+1]);
        if (n == 0) dt_sh = dt;
    }
    {
        int i = threadIdx.x;
        int cj = i >> 5, n = i & 31;
        size_t base = (((size_t)(c0+cj)*256 + h)*32 + n)*2;
        cc[cj][n] = make_float2(C_ri[base+0], C_ri[base+1]);
    }
    __syncthreads();
    if (l >= LF) return;

    float4 zt = ZT[l];
    const float zx = zt.x, zy = zt.y;
    float r0x[9], r0y[9], r1x[9], r1y[9];
    #pragma unroll
    for (int j=0;j<9;++j){ r0x[j]=0.f; r0y[j]=0.f; r1x[j]=0.f; r1y[j]=0.f; }

    #pragma unroll 1
    for (int n=0; n<32; ++n){
        float2 wn = wv[n];
        float dx = zx - wn.x;
        float dy = zy - wn.y;
        float ey = zy + wn.y;
        float ip = frcp(dx*dx + dy*dy);
        float im = frcp(dx*dx + ey*ey);
        float cpx = dx*ip, cpy = -dy*ip;
        float cmx = dx*im, cmy = -ey*im;
        float2 bn = bv[n];
        float br = bn.x, bi = bn.y;
        float t0x = br*cpx - bi*cpy, t0y = br*cpy + bi*cpx;
        float t1x = br*cmx + bi*cmy, t1y = br*cmy - bi*cmx;
        float2 pn = pv[n];
        float pr = pn.x, pi = pn.y;
        float t2x = pr*cpx - pi*cpy, t2y = pr*cpy + pi*cpx;
        float t3x = pr*cmx + pi*cmy, t3y = pr*cmy - pi*cmx;
        float u0 = t0x+t1x, v0 = t1y-t0y, s0 = t0y+t1y, q0 = t0x-t1x;
        float u1 = t2x+t3x, v1 = t3y-t2y, s1 = t2y+t3y, q1 = t2x-t3x;
        #pragma unroll
        for (int j=0;j<8;++j){
            float2 c = cc[j][n];
            float a = c.x, b = c.y;
            r0x[j] = fmaf(a,u0, fmaf(b,v0, r0x[j]));
            r0y[j] = fmaf(a,s0, fmaf(b,q0, r0y[j]));
            r1x[j] = fmaf(a,u1, fmaf(b,v1, r1x[j]));
            r1y[j] = fmaf(a,s1, fmaf(b,q1, r1y[j]));
        }
        r0x[8] = fmaf(pr,u0, fmaf(-pi,v0, r0x[8]));
        r0y[8] = fmaf(pr,s0, fmaf(-pi,q0, r0y[8]));
        r1x[8] = fmaf(pr,u1, fmaf(-pi,v1, r1x[8]));
        r1y[8] = fmaf(pr,s1, fmaf(-pi,q1, r1y[8]));
    }

    float dt = dt_sh;
    #pragma unroll
    for (int j=0;j<9;++j){ r0x[j]*=dt; r0y[j]*=dt; r1x[j]*=dt; r1y[j]*=dt; }
    float drr = 1.0f + r1x[8], dii = r1y[8];
    float idn = frcp(drr*drr + dii*dii);
    float gx = (r0x[8]*drr + r0y[8]*dii)*idn;
    float gy = (r0y[8]*drr - r0x[8]*dii)*idn;
    float tfx = zt.z, tfy = zt.w;
    #pragma unroll
    for (int j=0;j<8;++j){
        float kr = r0x[j] - (gx*r1x[j] - gy*r1y[j]);
        float ki = r0y[j] - (gx*r1y[j] + gy*r1x[j]);
        KF[((size_t)((c0+j)*256+h))*1026 + l] = make_float2(kr*tfx - ki*tfy, kr*tfy + ki*tfx);
    }
}

// ---------------- radix-8 butterfly on registers (post-twiddle) ----------------
template<bool INV>
__device__ __forceinline__ void bfly8(float2 v[8]){
    float2 e0,e1,e2,e3,o0,o1,o2,o3;
    {   // DFT4 of v0,v2,v4,v6
        float t0x=v[0].x+v[4].x, t0y=v[0].y+v[4].y;
        float t1x=v[0].x-v[4].x, t1y=v[0].y-v[4].y;
        float t2x=v[2].x+v[6].x, t2y=v[2].y+v[6].y;
        float t3x=v[2].x-v[6].x, t3y=v[2].y-v[6].y;
        e0 = make_float2(t0x+t2x, t0y+t2y);
        e2 = make_float2(t0x-t2x, t0y-t2y);
        if (!INV){ e1 = make_float2(t1x+t3y, t1y-t3x); e3 = make_float2(t1x-t3y, t1y+t3x); }
        else     { e1 = make_float2(t1x-t3y, t1y+t3x); e3 = make_float2(t1x+t3y, t1y-t3x); }
    }
    {   // DFT4 of v1,v3,v5,v7
        float t0x=v[1].x+v[5].x, t0y=v[1].y+v[5].y;
        float t1x=v[1].x-v[5].x, t1y=v[1].y-v[5].y;
        float t2x=v[3].x+v[7].x, t2y=v[3].y+v[7].y;
        float t3x=v[3].x-v[7].x, t3y=v[3].y-v[7].y;
        o0 = make_float2(t0x+t2x, t0y+t2y);
        o2 = make_float2(t0x-t2x, t0y-t2y);
        if (!INV){ o1 = make_float2(t1x+t3y, t1y-t3x); o3 = make_float2(t1x-t3y, t1y+t3x); }
        else     { o1 = make_float2(t1x-t3y, t1y+t3x); o3 = make_float2(t1x+t3y, t1y-t3x); }
    }
    const float RC = 0.70710678118654752f;
    float2 w1o1, w2o2, w3o3;
    if (!INV){
        w1o1 = make_float2(RC*(o1.x+o1.y), RC*(o1.y-o1.x));    // (1-i)/sqrt2
        w2o2 = make_float2(o2.y, -o2.x);                       // -i
        w3o3 = make_float2(RC*(o3.y-o3.x), RC*(-o3.x-o3.y));   // -(1+i)/sqrt2
    } else {
        w1o1 = make_float2(RC*(o1.x-o1.y), RC*(o1.y+o1.x));    // (1+i)/sqrt2
        w2o2 = make_float2(-o2.y, o2.x);                       // i
        w3o3 = make_float2(RC*(-o3.x-o3.y), RC*(o3.x-o3.y));   // (-1+i)/sqrt2
    }
    v[0] = make_float2(e0.x+o0.x,   e0.y+o0.y);
    v[1] = make_float2(e1.x+w1o1.x, e1.y+w1o1.y);
    v[2] = make_float2(e2.x+w2o2.x, e2.y+w2o2.y);
    v[3] = make_float2(e3.x+w3o3.x, e3.y+w3o3.y);
    v[4] = make_float2(e0.x-o0.x,   e0.y-o0.y);
    v[5] = make_float2(e1.x-w1o1.x, e1.y-w1o1.y);
    v[6] = make_float2(e2.x-w2o2.x, e2.y-w2o2.y);
    v[7] = make_float2(e3.x-w3o3.x, e3.y-w3o3.y);
}

// ---------------- fft2048 = radix-4 (cross-wave) x 512-FFT (wave-local) ------
//  - input element base r0 is a per-thread parameter (thread holds r0+256m).
//  - REGOUT: g3's result stays in registers (v[q] = bin jbase+256q,
//    jbase = 4*(t&63)+(t>>6)); else bins land at binslot(j) in B.
template<bool INV, bool REGOUT>
__device__ __forceinline__ void fftR(float2 v[8], int r0, float2* __restrict__ A, float2* __restrict__ B){
    const int t = threadIdx.x;
    #pragma unroll
    for (int half=0; half<2; ++half){
        int r = r0 + half*256;
        float2 x0=v[half], x1=v[2+half], x2=v[4+half], x3=v[6+half];
        float t0x=x0.x+x2.x, t0y=x0.y+x2.y;
        float t1x=x0.x-x2.x, t1y=x0.y-x2.y;
        float t2x=x1.x+x3.x, t2y=x1.y+x3.y;
        float t3x=x1.x-x3.x, t3y=x1.y-x3.y;
        float2 y0 = make_float2(t0x+t2x, t0y+t2y);
        float2 y2 = make_float2(t0x-t2x, t0y-t2y);
        float2 y1, y3;
        if (!INV){ y1 = make_float2(t1x+t3y, t1y-t3x); y3 = make_float2(t1x-t3y, t1y+t3x); }
        else     { y1 = make_float2(t1x-t3y, t1y+t3x); y3 = make_float2(t1x+t3y, t1y-t3x); }
        float2 w1 = twid((float)r * (1.0f/2048.0f));
        if (INV) w1.y = -w1.y;
        float2 w2 = cmulf(w1,w1);
        float2 w3 = cmulf(w2,w1);
        A[gslot(0,r)] = y0;
        A[gslot(1,r)] = cmulf(y1,w1);
        A[gslot(2,r)] = cmulf(y2,w2);
        A[gslot(3,r)] = cmulf(y3,w3);
    }
    __syncthreads();
    const int w = t >> 6, l = t & 63;
    // ---- g1: NS=1, A -> B (wave-local) ----
    {
        float2 u[8];
        #pragma unroll
        for (int m=0;m<8;++m) u[m] = A[gslot(w, l + 64*m)];
        bfly8<INV>(u);
        #pragma unroll
        for (int q=0;q<8;++q) B[gslot(w, 8*l+q)] = u[q];
    }
    lds_fence();
    // ---- g2: NS=8, B -> A (wave-local) ----
    {
        float2 u[8];
        #pragma unroll
        for (int m=0;m<8;++m) u[m] = B[gslot(w, l + 64*m)];
        int jm = l & 7;
        float2 w1 = twid((float)jm * (1.0f/64.0f));
        if (INV) w1.y = -w1.y;
        float2 wc = w1;
        #pragma unroll
        for (int m=1;m<8;++m){ u[m] = cmulf(u[m], wc); if (m<7) wc = cmulf(wc, w1); }
        bfly8<INV>(u);
        int d = ((l - jm) << 3) + jm;
        #pragma unroll
        for (int q=0;q<8;++q) A[gslot(w, d + q*8)] = u[q];
    }
    lds_fence();
    // ---- g3: NS=64, A -> regs or B (wave-local) ----
    {
        float2 u[8];
        #pragma unroll
        for (int m=0;m<8;++m) u[m] = A[gslot(w, l + 64*m)];
        float2 w1 = twid((float)l * (1.0f/512.0f));
        if (INV) w1.y = -w1.y;
        float2 wc = w1;
        #pragma unroll
        for (int m=1;m<8;++m){ u[m] = cmulf(u[m], wc); if (m<7) wc = cmulf(wc, w1); }
        bfly8<INV>(u);
        if constexpr (REGOUT){
            #pragma unroll
            for (int q=0;q<8;++q) v[q] = u[q];      // bin 4l + w + 256q
        } else {
            #pragma unroll
            for (int q=0;q<8;++q) B[gslot(w, l + q*64)] = u[q];
        }
    }
    __syncthreads();
}

// ---------------- kernel C2: pd rows -> packed even/odd 4096-bin spectra ---------
__global__ __launch_bounds__(256,2) void kernC2(const float* __restrict__ pd,
                                                float2* __restrict__ PDE, float2* __restrict__ PDO){
    __shared__ float2 A[4*GS], Bb[4*GS];
    const int t = threadIdx.x;
    const int h = blockIdx.x;
    const float* p0 = pd + (size_t)h * 2048;
    const float* p1 = pd + (size_t)(256 + h) * 2048;
    float2 z[8], v[8];
    #pragma unroll
    for (int m=0;m<8;++m){
        int j = t + m*256;
        z[m] = make_float2(p0[j], p1[j]);
        v[m] = z[m];
    }
    fftR<false,false>(v, t, A, Bb);           // bins in Bb (binslot layout)
    float2* oe = PDE + (size_t)h * 2048;
    #pragma unroll
    for (int m=0;m<8;++m){ int j = t + m*256; oe[j] = Bb[binslot(j)]; }
    #pragma unroll
    for (int m=0;m<8;++m){
        int j = t + m*256;
        v[m] = cmulf(twid((float)j * (1.0f/4096.0f)), z[m]);   // * e^{-2pi i j/4096}
    }
    fftR<false,false>(v, t, A, Bb);
    float2* oo = PDO + (size_t)h * 2048;
    #pragma unroll
    for (int m=0;m<8;++m){ int j = t + m*256; oo[j] = Bb[binslot(j)]; }
}

// ---------------- fused kernel F v11 (unchanged: 144.8us, VALU 49%) ----------
__global__ __launch_bounds__(256,2) void kernF(const float2* __restrict__ KFb,
                                               const float2* __restrict__ PDE,
                                               const float2* __restrict__ PDO,
                                               const float* __restrict__ DCT,
                                               float* __restrict__ out){
    __shared__ float2 A[4*GS], Bb[4*GS];
    __shared__ float2 pde_s[2048], pdo_s[2048];
    const int t = threadIdx.x;
    const int h = blockIdx.x;
    const int cq = blockIdx.y;                 // 0..1, 16 channels (8 pairs) each
    const int jbase = ((t & 63) << 2) | (t >> 6);
    {
        const float2* pe = PDE + (size_t)h * 2048;
        const float2* po = PDO + (size_t)h * 2048;
        #pragma unroll
        for (int m=0;m<8;++m){
            int j = t + m*256;
            pde_s[j] = pe[j];
            pdo_s[j] = po[j];
        }
    }
    float accr[8], acci[8];
    #pragma unroll
    for (int m=0;m<8;++m){ accr[m]=0.f; acci[m]=0.f; }
    __syncthreads();                            // pde_s/pdo_s visible to all

    #pragma unroll 1
    for (int pp=0; pp<8; ++pp){
        const int ca = cq*16 + pp*2;
        const float2* ra = KFb + (size_t)(ca*256+h)*1026;
        const float2* rb = KFb + (size_t)((ca+1)*256+h)*1026;

        // prefetch PERMUTED dct: linear load at t+256m yields dct[jbase+256m]
        float dcva[8], dcvb[8];
        {
            const float* dcta = DCT + (size_t)(h*32 + ca) * 2048;
            const float* dctb = dcta + 2048;
            #pragma unroll
            for (int m=0;m<8;++m){
                int j = t + m*256;
                dcva[m] = dcta[j] * (1.0f/4096.0f);
                dcvb[m] = dctb[j] * (1.0f/4096.0f);
            }
        }
        float2 v[8];

        // ---- Phase E, channel a: ifft(pde * Herm(kf_a)); reg-consume ----
        #pragma unroll
        for (int m=0;m<8;++m){
            int j = t + m*256;
            float2 u;
            if (j <= 1024) u = ra[j];
            else { float2 w = ra[2048-j]; u = make_float2(w.x, -w.y); }  // Hermitian
            v[m] = cmulf(pde_s[j], u);
        }
        fftR<true,true>(v, t, A, Bb);          // v[m] = x_e at sample jbase+256m
        #pragma unroll
        for (int m=0;m<8;++m){
            accr[m] = fmaf(v[m].x, dcva[m], accr[m]);
            acci[m] = fmaf(v[m].y, dcva[m], acci[m]);
        }
        // ---- Phase E, channel b ----
        #pragma unroll
        for (int m=0;m<8;++m){
            int j = t + m*256;
            float2 u;
            if (j <= 1024) u = rb[j];
            else { float2 w = rb[2048-j]; u = make_float2(w.x, -w.y); }
            v[m] = cmulf(pde_s[j], u);
        }
        fftR<true,true>(v, t, A, Bb);
        #pragma unroll
        for (int m=0;m<8;++m){
            accr[m] = fmaf(v[m].x, dcvb[m], accr[m]);
            acci[m] = fmaf(v[m].y, dcvb[m], acci[m]);
        }

        // ---- Phase O (paired): ifft(Herm_a + i*Herm_b) = 2048*(k_a + i*k_b) ----
        #pragma unroll
        for (int m=0;m<8;++m){
            int j = t + m*256;
            float2 va, vb;
            if (j <= 1024){ va = ra[j]; vb = rb[j]; }
            else {
                float2 u = ra[2048-j]; va = make_float2(u.x, -u.y);
                float2 w = rb[2048-j]; vb = make_float2(w.x, -w.y);
            }
            v[m] = make_float2(va.x - vb.y, va.y + vb.x);
        }
        fftR<true,true>(v, t, A, Bb);          // v[m] = packed k sample jbase+256m (x2048)
        // modulate in regs: sample n = jbase+256m, * e^{-2pi i n/4096}
        #pragma unroll
        for (int m=0;m<8;++m){
            float2 kk = v[m];
            kk.x *= (1.0f/2048.0f); kk.y *= (1.0f/2048.0f);
            v[m] = cmulf(kk, twid((float)(jbase + 256*m) * (1.0f/4096.0f)));
        }
        fftR<false,false>(v, jbase, A, Bb);    // Z in Bb at binslot (needs 2047-j gather)

        // unpack + products (cross reads of Bb, behind fftR's final sync)
        float2 pa[8], sb[8];
        #pragma unroll
        for (int m=0;m<8;++m){
            int j  = t + m*256;
            float2 z  = Bb[binslot(j)];
            float2 zm = Bb[binslot(2047 - j)];
            float2 Ka = make_float2(0.5f*(z.x + zm.x), 0.5f*(z.y - zm.y));
            float2 Kb = make_float2(0.5f*(z.y + zm.y), 0.5f*(zm.x - z.x));
            float2 pov = pdo_s[j];
            pa[m] = cmulf(pov, Ka);
            sb[m] = cmulf(pov, Kb);
        }
        // ifft channel a -> regs; rotate by e^{+2pi i jq/4096}; accumulate
        fftR<true,true>(pa, t, A, Bb);
        #pragma unroll
        for (int m=0;m<8;++m){
            float2 w = twid((float)(jbase + 256*m) * (1.0f/4096.0f));
            float2 ee = make_float2(w.x, -w.y);
            float2 rot = cmulf(ee, pa[m]);
            accr[m] = fmaf(rot.x, dcva[m], accr[m]);
            acci[m] = fmaf(rot.y, dcva[m], acci[m]);
        }
        // ifft channel b -> regs
        fftR<true,true>(sb, t, A, Bb);
        #pragma unroll
        for (int m=0;m<8;++m){
            float2 w = twid((float)(jbase + 256*m) * (1.0f/4096.0f));
            float2 ee = make_float2(w.x, -w.y);
            float2 rot = cmulf(ee, sb[m]);
            accr[m] = fmaf(rot.x, dcvb[m], accr[m]);
            acci[m] = fmaf(rot.y, dcvb[m], acci[m]);
        }
    }
    #pragma unroll
    for (int m=0;m<8;++m){
        int jq = jbase + 256*m;
        atomicAdd(&out[((size_t)h)*2048 + jq],       accr[m]);   // batch 0 (Re)
        atomicAdd(&out[((size_t)(256+h))*2048 + jq], acci[m]);   // batch 1 (Im)
    }
}

extern "C" void kernel_launch(void* const* d_in, const int* in_sizes, int n_in,
                              void* d_out, int out_size, void* d_ws, size_t ws_size,
                              hipStream_t stream) {
    const float* log_dt = (const float*)d_in[0];
    const float* B_ri   = (const float*)d_in[1];
    const float* P_ri   = (const float*)d_in[2];
    const float* C_ri   = (const float*)d_in[3];
    const float* ivw    = (const float*)d_in[4];
    const float* wimag  = (const float*)d_in[5];
    const float* dC     = (const float*)d_in[6];
    const float* pd     = (const float*)d_in[7];

    char* ws = (char*)d_ws;
    float4* ZT  = (float4*)(ws + OFF_ZT);
    float2* KF  = (float2*)(ws + OFF_KF);
    float2* PDE = (float2*)(ws + OFF_PDF);
    float2* PDO = (float2*)(ws + OFF_PDF + 256*2048*sizeof(float2));
    float*  DCT = (float*) (ws + OFF_DCT);
    float* out = (float*)d_out;

    hipMemsetAsync(out, 0, (size_t)out_size * sizeof(float), stream);
    initk<<<5, 256, 0, stream>>>(ZT);
    transpose_dC<<<dim3(256,8), dim3(32,8), 0, stream>>>(dC, DCT);
    cauchy_k<<<dim3(5,256,4), 256, 0, stream>>>(log_dt, B_ri, P_ri, C_ri, ivw, wimag, ZT, KF);
    kernC2<<<256, 256, 0, stream>>>(pd, PDE, PDO);
    kernF<<<dim3(256,2), 256, 0, stream>>>((const float2*)KF, PDE, PDO, DCT, out);
}